// Round 1
// baseline (194.502 us; speedup 1.0000x reference)
//
#include <hip/hip_runtime.h>
#include <math.h>

#define Bx   32
#define Sx   1024
#define ATTx 512
#define ENCx 512

// tanh(x) = 1 - 2/(exp(2x)+1); exp2-based, saturates correctly at +-inf.
__device__ __forceinline__ float fast_tanh(float x) {
    float e = __builtin_amdgcn_exp2f(x * 2.8853900817779268f); // 2*log2(e)
    return fmaf(-2.0f, __builtin_amdgcn_rcpf(e + 1.0f), 1.0f);
}

// ---------------------------------------------------------------------------
// Kernel A: qm/qc[b,a] = dot(dec_h[b,:], W[a,:]) + bias[a]   (wave per output)
// Extra block (blockIdx==8192) computes weight-normed v vectors.
// ---------------------------------------------------------------------------
__global__ __launch_bounds__(256) void precompute_kernel(
    const float* __restrict__ dec,
    const float* __restrict__ Wm, const float* __restrict__ bm,
    const float* __restrict__ Wc, const float* __restrict__ bc,
    const float* __restrict__ vm, const float* __restrict__ gm,
    const float* __restrict__ vc, const float* __restrict__ gc,
    float* __restrict__ qm, float* __restrict__ qc,
    float* __restrict__ vmn, float* __restrict__ vcn)
{
    if (blockIdx.x == 8192) {
        int t = threadIdx.x;
        int lane = t & 63, wid = t >> 6;
        float sm_ = 0.f, sc_ = 0.f;
        for (int i = t; i < ATTx; i += 256) {
            float a = vm[i]; sm_ += a * a;
            float c = vc[i]; sc_ += c * c;
        }
        #pragma unroll
        for (int off = 32; off; off >>= 1) {
            sm_ += __shfl_xor(sm_, off, 64);
            sc_ += __shfl_xor(sc_, off, 64);
        }
        __shared__ float wsm[4], wsc[4];
        if (lane == 0) { wsm[wid] = sm_; wsc[wid] = sc_; }
        __syncthreads();
        float nm = sqrtf(wsm[0] + wsm[1] + wsm[2] + wsm[3]);
        float nc = sqrtf(wsc[0] + wsc[1] + wsc[2] + wsc[3]);
        float sg_m = gm[0] / nm, sg_c = gc[0] / nc;
        for (int i = t; i < ATTx; i += 256) {
            vmn[i] = vm[i] * sg_m;
            vcn[i] = vc[i] * sg_c;
        }
        return;
    }
    int gw   = blockIdx.x * 4 + (threadIdx.x >> 6);  // 0..32767
    int lane = threadIdx.x & 63;
    int mat  = gw >> 14;           // 0: mono, 1: chunk
    int idx  = gw & 16383;
    int b = idx >> 9, a = idx & 511;
    const float4* W4 = (const float4*)((mat ? Wc : Wm) + (size_t)a * 512);
    const float4* d4 = (const float4*)(dec + (size_t)b * 512);
    float4 w0 = W4[lane * 2], w1 = W4[lane * 2 + 1];
    float4 x0 = d4[lane * 2], x1 = d4[lane * 2 + 1];
    float s = w0.x * x0.x + w0.y * x0.y + w0.z * x0.z + w0.w * x0.w
            + w1.x * x1.x + w1.y * x1.y + w1.z * x1.z + w1.w * x1.w;
    #pragma unroll
    for (int off = 32; off; off >>= 1) s += __shfl_xor(s, off, 64);
    if (lane == 0) {
        float bias = (mat ? bc : bm)[a];
        (mat ? qc : qm)[b * ATTx + a] = s + bias;
    }
}

// ---------------------------------------------------------------------------
// Kernel B: fused dual energy. One wave per (b,s); key read ONCE for both.
// ---------------------------------------------------------------------------
__global__ __launch_bounds__(256) void energy_kernel(
    const float* __restrict__ key,
    const float* __restrict__ qm, const float* __restrict__ qc,
    const float* __restrict__ vmn, const float* __restrict__ vcn,
    const float* __restrict__ vbm, const float* __restrict__ rm,
    const float* __restrict__ vbc, const float* __restrict__ rc,
    float* __restrict__ mono_e, float* __restrict__ chunk_e)
{
    int gw   = blockIdx.x * 4 + (threadIdx.x >> 6);   // 0..32767 = b*1024+s
    int lane = threadIdx.x & 63;
    int b = gw >> 10;
    const float4* k4  = (const float4*)(key + (size_t)gw * ATTx);
    const float4* qm4 = (const float4*)(qm + b * ATTx);
    const float4* qc4 = (const float4*)(qc + b * ATTx);
    const float4* vm4 = (const float4*)vmn;
    const float4* vc4 = (const float4*)vcn;
    float em = 0.f, ec = 0.f;
    #pragma unroll
    for (int j = 0; j < 2; j++) {
        int i = lane * 2 + j;
        float4 k  = k4[i];
        float4 qa = qm4[i], qb = qc4[i], va = vm4[i], vb = vc4[i];
        em += fast_tanh(k.x + qa.x) * va.x + fast_tanh(k.y + qa.y) * va.y
            + fast_tanh(k.z + qa.z) * va.z + fast_tanh(k.w + qa.w) * va.w;
        ec += fast_tanh(k.x + qb.x) * vb.x + fast_tanh(k.y + qb.y) * vb.y
            + fast_tanh(k.z + qb.z) * vb.z + fast_tanh(k.w + qb.w) * vb.w;
    }
    #pragma unroll
    for (int off = 32; off; off >>= 1) {
        em += __shfl_xor(em, off, 64);
        ec += __shfl_xor(ec, off, 64);
    }
    if (lane == 0) {
        mono_e[gw]  = em + vbm[0] + rm[0];
        chunk_e[gw] = ec + vbc[0] + rc[0];
    }
}

// ---------------------------------------------------------------------------
// Kernel C: per-row scans + moving windows. One block (1024 thr) per batch row.
// ---------------------------------------------------------------------------
__global__ __launch_bounds__(1024) void scan_kernel(
    const float* __restrict__ mono_e, const float* __restrict__ chunk_e,
    const float* __restrict__ prev_att, const float* __restrict__ noise,
    float* __restrict__ beta)
{
    int b = blockIdx.x, t = threadIdx.x;       // t == s
    int lane = t & 63, wid = t >> 6;           // 16 waves
    __shared__ float wred[16];
    __shared__ float arrA[1024];
    __shared__ float arrB[1024];
    __shared__ float arrC[1024];

    size_t base = (size_t)b * Sx;
    float pa = prev_att[base + t];

    // ---- row sum of prev_att ----
    float sum = pa;
    #pragma unroll
    for (int off = 32; off; off >>= 1) sum += __shfl_xor(sum, off, 64);
    if (lane == 0) wred[wid] = sum;
    __syncthreads();
    float psum = 0.f;
    #pragma unroll
    for (int i = 0; i < 16; i++) psum += wred[i];

    // ---- p_sel ----
    float me = mono_e[base + t], nz = noise[base + t];
    float p = 1.0f / (1.0f + expf(-(me + nz)));
    if (t == Sx - 1) p = 1.0f;
    float om = 1.0f - p;

    // ---- exclusive cumprod of (1-p): wave inclusive scan + cross-wave ----
    float v = om;
    #pragma unroll
    for (int d = 1; d < 64; d <<= 1) {
        float tv = __shfl_up(v, d, 64);
        if (lane >= d) v *= tv;
    }
    __syncthreads();                       // psum reads of wred done
    if (lane == 63) wred[wid] = v;
    __syncthreads();
    float pre = 1.0f;
    for (int i = 0; i < wid; i++) pre *= wred[i];
    float incp = pre * v;                  // inclusive cumprod at t
    arrA[t] = incp;
    __syncthreads();
    float cp = (t == 0) ? 1.0f : arrA[t - 1];   // exclusive

    // ---- inclusive cumsum of prev_norm / clip(cp) ----
    float cpc = fminf(fmaxf(cp, 1e-20f), 1.0f);
    float y = (pa / psum) / cpc;
    float w2 = y;
    #pragma unroll
    for (int d = 1; d < 64; d <<= 1) {
        float tv = __shfl_up(w2, d, 64);
        if (lane >= d) w2 += tv;
    }
    __syncthreads();                       // arrA[t-1] reads done, wred reads done
    if (lane == 63) wred[wid] = w2;
    __syncthreads();
    float pres = 0.f;
    for (int i = 0; i < wid; i++) pres += wred[i];
    float cs = pres + w2;
    float alpha = p * cp * cs;

    // ---- chunk energy windows (w = 8) ----
    float ce = chunk_e[base + t];
    arrA[t] = ce;                          // safe: all arrA reads happened before barriers above
    __syncthreads();
    float mx = ce;
    #pragma unroll
    for (int j = 1; j < 8; j++) { int i2 = t - j; if (i2 >= 0) mx = fmaxf(mx, arrA[i2]); }
    float eu = expf(ce - mx);
    arrB[t] = eu;
    __syncthreads();
    float den = eu;
    #pragma unroll
    for (int j = 1; j < 8; j++) { int i2 = t - j; if (i2 >= 0) den += arrB[i2]; }
    den = fmaxf(den, 1e-10f);
    arrC[t] = alpha / den;
    __syncthreads();
    float acc = 0.f;
    #pragma unroll
    for (int j = 0; j < 8; j++) { int i2 = t + j; if (i2 < Sx) acc += arrC[i2]; }
    beta[base + t] = eu * acc;
}

// ---------------------------------------------------------------------------
// Kernel D: context[b,d] = sum_s beta[b,s] * value[b,s,d]
// grid = B*32 blocks, each covers 32 s-positions, full d; atomicAdd partials.
// ---------------------------------------------------------------------------
__global__ __launch_bounds__(256) void context_kernel(
    const float* __restrict__ beta, const float* __restrict__ value,
    float* __restrict__ out)
{
    int blk = blockIdx.x;
    int b = blk >> 5, chunk = blk & 31;
    int s0 = chunk * 32;
    int t = threadIdx.x;                  // covers d = 2t, 2t+1
    const float2* v2 = (const float2*)(value + ((size_t)(b * Sx + s0)) * ENCx) + t;
    const float*  bp = beta + (size_t)b * Sx + s0;
    float2 acc = {0.f, 0.f};
    #pragma unroll 4
    for (int i = 0; i < 32; i++) {
        float w = bp[i];
        float2 vv = v2[(size_t)i * (ENCx / 2)];
        acc.x = fmaf(w, vv.x, acc.x);
        acc.y = fmaf(w, vv.y, acc.y);
    }
    atomicAdd(&out[b * ENCx + 2 * t],     acc.x);
    atomicAdd(&out[b * ENCx + 2 * t + 1], acc.y);
}

// ---------------------------------------------------------------------------
extern "C" void kernel_launch(void* const* d_in, const int* in_sizes, int n_in,
                              void* d_out, int out_size, void* d_ws, size_t ws_size,
                              hipStream_t stream) {
    const float* dec      = (const float*)d_in[0];
    const float* key      = (const float*)d_in[1];
    const float* value    = (const float*)d_in[2];
    const float* prev_att = (const float*)d_in[3];
    const float* noise    = (const float*)d_in[4];
    const float* Wm  = (const float*)d_in[5];
    const float* bm  = (const float*)d_in[6];
    const float* vm  = (const float*)d_in[7];
    const float* gm  = (const float*)d_in[8];
    const float* vbm = (const float*)d_in[9];
    const float* rm  = (const float*)d_in[10];
    const float* Wc  = (const float*)d_in[11];
    const float* bc  = (const float*)d_in[12];
    const float* vc  = (const float*)d_in[13];
    const float* gc  = (const float*)d_in[14];
    const float* vbc = (const float*)d_in[15];
    const float* rc  = (const float*)d_in[16];
    float* out = (float*)d_out;

    float* ws      = (float*)d_ws;
    float* qm      = ws;                   // [B,ATT]   16384
    float* qc      = qm + Bx * ATTx;       // 16384
    float* vmn     = qc + Bx * ATTx;       // 512
    float* vcn     = vmn + ATTx;           // 512
    float* mono_e  = vcn + ATTx;           // [B,S] 32768
    float* chunk_e = mono_e + Bx * Sx;     // 32768
    float* beta    = chunk_e + Bx * Sx;    // 32768

    hipMemsetAsync(out, 0, (size_t)out_size * sizeof(float), stream);
    precompute_kernel<<<8193, 256, 0, stream>>>(dec, Wm, bm, Wc, bc, vm, gm, vc, gc,
                                                qm, qc, vmn, vcn);
    energy_kernel<<<8192, 256, 0, stream>>>(key, qm, qc, vmn, vcn,
                                            vbm, rm, vbc, rc, mono_e, chunk_e);
    scan_kernel<<<Bx, 1024, 0, stream>>>(mono_e, chunk_e, prev_att, noise, beta);
    context_kernel<<<Bx * 32, 256, 0, stream>>>(beta, value, out);
}

// Round 3
// 194.350 us; speedup vs baseline: 1.0008x; 1.0008x over previous
//
#include <hip/hip_runtime.h>
#include <math.h>

#define Bx   32
#define Sx   1024
#define ATTx 512
#define ENCx 512

typedef float vfloat4 __attribute__((ext_vector_type(4)));
typedef float vfloat2 __attribute__((ext_vector_type(2)));

// tanh(x) = 1 - 2/(exp(2x)+1); exp2-based, saturates correctly at +-inf.
__device__ __forceinline__ float fast_tanh(float x) {
    float e = __builtin_amdgcn_exp2f(x * 2.8853900817779268f); // 2*log2(e)
    return fmaf(-2.0f, __builtin_amdgcn_rcpf(e + 1.0f), 1.0f);
}

// ---------------------------------------------------------------------------
// Kernel A: qm/qc[b,a] = dot(dec_h[b,:], W[a,:]) + bias[a]   (wave per output)
// Extra block (blockIdx==8192) computes weight-normed v vectors.
// ---------------------------------------------------------------------------
__global__ __launch_bounds__(256) void precompute_kernel(
    const float* __restrict__ dec,
    const float* __restrict__ Wm, const float* __restrict__ bm,
    const float* __restrict__ Wc, const float* __restrict__ bc,
    const float* __restrict__ vm, const float* __restrict__ gm,
    const float* __restrict__ vc, const float* __restrict__ gc,
    float* __restrict__ qm, float* __restrict__ qc,
    float* __restrict__ vmn, float* __restrict__ vcn)
{
    if (blockIdx.x == 8192) {
        int t = threadIdx.x;
        int lane = t & 63, wid = t >> 6;
        float sm_ = 0.f, sc_ = 0.f;
        for (int i = t; i < ATTx; i += 256) {
            float a = vm[i]; sm_ += a * a;
            float c = vc[i]; sc_ += c * c;
        }
        #pragma unroll
        for (int off = 32; off; off >>= 1) {
            sm_ += __shfl_xor(sm_, off, 64);
            sc_ += __shfl_xor(sc_, off, 64);
        }
        __shared__ float wsm[4], wsc[4];
        if (lane == 0) { wsm[wid] = sm_; wsc[wid] = sc_; }
        __syncthreads();
        float nm = sqrtf(wsm[0] + wsm[1] + wsm[2] + wsm[3]);
        float nc = sqrtf(wsc[0] + wsc[1] + wsc[2] + wsc[3]);
        float sg_m = gm[0] / nm, sg_c = gc[0] / nc;
        for (int i = t; i < ATTx; i += 256) {
            vmn[i] = vm[i] * sg_m;
            vcn[i] = vc[i] * sg_c;
        }
        return;
    }
    int gw   = blockIdx.x * 4 + (threadIdx.x >> 6);  // 0..32767
    int lane = threadIdx.x & 63;
    int mat  = gw >> 14;           // 0: mono, 1: chunk
    int idx  = gw & 16383;
    int b = idx >> 9, a = idx & 511;
    const float4* W4 = (const float4*)((mat ? Wc : Wm) + (size_t)a * 512);
    const float4* d4 = (const float4*)(dec + (size_t)b * 512);
    float4 w0 = W4[lane * 2], w1 = W4[lane * 2 + 1];
    float4 x0 = d4[lane * 2], x1 = d4[lane * 2 + 1];
    float s = w0.x * x0.x + w0.y * x0.y + w0.z * x0.z + w0.w * x0.w
            + w1.x * x1.x + w1.y * x1.y + w1.z * x1.z + w1.w * x1.w;
    #pragma unroll
    for (int off = 32; off; off >>= 1) s += __shfl_xor(s, off, 64);
    if (lane == 0) {
        float bias = (mat ? bc : bm)[a];
        (mat ? qc : qm)[b * ATTx + a] = s + bias;
    }
}

// ---------------------------------------------------------------------------
// Kernel B: fused dual energy. One wave per (b,s); key read ONCE for both.
// key is streamed exactly once -> non-temporal.
// ---------------------------------------------------------------------------
__global__ __launch_bounds__(256) void energy_kernel(
    const float* __restrict__ key,
    const float* __restrict__ qm, const float* __restrict__ qc,
    const float* __restrict__ vmn, const float* __restrict__ vcn,
    const float* __restrict__ vbm, const float* __restrict__ rm,
    const float* __restrict__ vbc, const float* __restrict__ rc,
    float* __restrict__ mono_e, float* __restrict__ chunk_e)
{
    int gw   = blockIdx.x * 4 + (threadIdx.x >> 6);   // 0..32767 = b*1024+s
    int lane = threadIdx.x & 63;
    int b = gw >> 10;
    const vfloat4* k4  = (const vfloat4*)(key + (size_t)gw * ATTx);
    const float4* qm4 = (const float4*)(qm + b * ATTx);
    const float4* qc4 = (const float4*)(qc + b * ATTx);
    const float4* vm4 = (const float4*)vmn;
    const float4* vc4 = (const float4*)vcn;
    float em = 0.f, ec = 0.f;
    #pragma unroll
    for (int j = 0; j < 2; j++) {
        int i = lane * 2 + j;
        vfloat4 k  = __builtin_nontemporal_load(k4 + i);
        float4 qa = qm4[i], qb = qc4[i], va = vm4[i], vb = vc4[i];
        em += fast_tanh(k.x + qa.x) * va.x + fast_tanh(k.y + qa.y) * va.y
            + fast_tanh(k.z + qa.z) * va.z + fast_tanh(k.w + qa.w) * va.w;
        ec += fast_tanh(k.x + qb.x) * vb.x + fast_tanh(k.y + qb.y) * vb.y
            + fast_tanh(k.z + qb.z) * vb.z + fast_tanh(k.w + qb.w) * vb.w;
    }
    #pragma unroll
    for (int off = 32; off; off >>= 1) {
        em += __shfl_xor(em, off, 64);
        ec += __shfl_xor(ec, off, 64);
    }
    if (lane == 0) {
        mono_e[gw]  = em + vbm[0] + rm[0];
        chunk_e[gw] = ec + vbc[0] + rc[0];
    }
}

// ---------------------------------------------------------------------------
// Kernel C: per-row scans + moving windows. One block (1024 thr) per batch row.
// Also zeroes out[b,:] so the context kernel can accumulate atomically
// (saves a separate memset dispatch; this kernel precedes context on stream).
// ---------------------------------------------------------------------------
__global__ __launch_bounds__(1024) void scan_kernel(
    const float* __restrict__ mono_e, const float* __restrict__ chunk_e,
    const float* __restrict__ prev_att, const float* __restrict__ noise,
    float* __restrict__ beta, float* __restrict__ out)
{
    int b = blockIdx.x, t = threadIdx.x;       // t == s
    int lane = t & 63, wid = t >> 6;           // 16 waves
    __shared__ float wred[16];
    __shared__ float arrA[1024];
    __shared__ float arrB[1024];
    __shared__ float arrC[1024];

    if (t < ENCx) out[b * ENCx + t] = 0.0f;    // zero context accumulator

    size_t base = (size_t)b * Sx;
    float pa = prev_att[base + t];

    // ---- row sum of prev_att ----
    float sum = pa;
    #pragma unroll
    for (int off = 32; off; off >>= 1) sum += __shfl_xor(sum, off, 64);
    if (lane == 0) wred[wid] = sum;
    __syncthreads();
    float psum = 0.f;
    #pragma unroll
    for (int i = 0; i < 16; i++) psum += wred[i];

    // ---- p_sel ----
    float me = mono_e[base + t], nz = noise[base + t];
    float p = 1.0f / (1.0f + expf(-(me + nz)));
    if (t == Sx - 1) p = 1.0f;
    float om = 1.0f - p;

    // ---- exclusive cumprod of (1-p): wave inclusive scan + cross-wave ----
    float v = om;
    #pragma unroll
    for (int d = 1; d < 64; d <<= 1) {
        float tv = __shfl_up(v, d, 64);
        if (lane >= d) v *= tv;
    }
    __syncthreads();                       // psum reads of wred done
    if (lane == 63) wred[wid] = v;
    __syncthreads();
    float pre = 1.0f;
    for (int i = 0; i < wid; i++) pre *= wred[i];
    float incp = pre * v;                  // inclusive cumprod at t
    arrA[t] = incp;
    __syncthreads();
    float cp = (t == 0) ? 1.0f : arrA[t - 1];   // exclusive

    // ---- inclusive cumsum of prev_norm / clip(cp) ----
    float cpc = fminf(fmaxf(cp, 1e-20f), 1.0f);
    float y = (pa / psum) / cpc;
    float w2 = y;
    #pragma unroll
    for (int d = 1; d < 64; d <<= 1) {
        float tv = __shfl_up(w2, d, 64);
        if (lane >= d) w2 += tv;
    }
    __syncthreads();                       // arrA[t-1] reads done, wred reads done
    if (lane == 63) wred[wid] = w2;
    __syncthreads();
    float pres = 0.f;
    for (int i = 0; i < wid; i++) pres += wred[i];
    float cs = pres + w2;
    float alpha = p * cp * cs;

    // ---- chunk energy windows (w = 8) ----
    float ce = chunk_e[base + t];
    arrA[t] = ce;                          // safe: all arrA reads happened before barriers above
    __syncthreads();
    float mx = ce;
    #pragma unroll
    for (int j = 1; j < 8; j++) { int i2 = t - j; if (i2 >= 0) mx = fmaxf(mx, arrA[i2]); }
    float eu = expf(ce - mx);
    arrB[t] = eu;
    __syncthreads();
    float den = eu;
    #pragma unroll
    for (int j = 1; j < 8; j++) { int i2 = t - j; if (i2 >= 0) den += arrB[i2]; }
    den = fmaxf(den, 1e-10f);
    arrC[t] = alpha / den;
    __syncthreads();
    float acc = 0.f;
    #pragma unroll
    for (int j = 0; j < 8; j++) { int i2 = t + j; if (i2 < Sx) acc += arrC[i2]; }
    beta[base + t] = eu * acc;
}

// ---------------------------------------------------------------------------
// Kernel D: context[b,d] = sum_s beta[b,s] * value[b,s,d]
// grid = B*16 blocks, each covers 64 s-positions, full d; atomicAdd partials.
// beta[s] is block-uniform per iteration -> scalar load. value non-temporal.
// ---------------------------------------------------------------------------
__global__ __launch_bounds__(256) void context_kernel(
    const float* __restrict__ beta, const float* __restrict__ value,
    float* __restrict__ out)
{
    int blk = blockIdx.x;
    int b = blk >> 4, chunk = blk & 15;
    int s0 = chunk * 64;
    int t = threadIdx.x;                  // covers d = 2t, 2t+1
    const vfloat2* v2 = (const vfloat2*)(value + ((size_t)(b * Sx + s0)) * ENCx) + t;
    const float*  bp = beta + (size_t)b * Sx + s0;
    float acx = 0.f, acy = 0.f;
    #pragma unroll 8
    for (int i = 0; i < 64; i++) {
        float w = bp[i];                                   // uniform -> s_load
        vfloat2 vv = __builtin_nontemporal_load(v2 + (size_t)i * (ENCx / 2));
        acx = fmaf(w, vv.x, acx);
        acy = fmaf(w, vv.y, acy);
    }
    atomicAdd(&out[b * ENCx + 2 * t],     acx);
    atomicAdd(&out[b * ENCx + 2 * t + 1], acy);
}

// ---------------------------------------------------------------------------
extern "C" void kernel_launch(void* const* d_in, const int* in_sizes, int n_in,
                              void* d_out, int out_size, void* d_ws, size_t ws_size,
                              hipStream_t stream) {
    const float* dec      = (const float*)d_in[0];
    const float* key      = (const float*)d_in[1];
    const float* value    = (const float*)d_in[2];
    const float* prev_att = (const float*)d_in[3];
    const float* noise    = (const float*)d_in[4];
    const float* Wm  = (const float*)d_in[5];
    const float* bm  = (const float*)d_in[6];
    const float* vm  = (const float*)d_in[7];
    const float* gm  = (const float*)d_in[8];
    const float* vbm = (const float*)d_in[9];
    const float* rm  = (const float*)d_in[10];
    const float* Wc  = (const float*)d_in[11];
    const float* bc  = (const float*)d_in[12];
    const float* vc  = (const float*)d_in[13];
    const float* gc  = (const float*)d_in[14];
    const float* vbc = (const float*)d_in[15];
    const float* rc  = (const float*)d_in[16];
    float* out = (float*)d_out;

    float* ws      = (float*)d_ws;
    float* qm      = ws;                   // [B,ATT]   16384
    float* qc      = qm + Bx * ATTx;       // 16384
    float* vmn     = qc + Bx * ATTx;       // 512
    float* vcn     = vmn + ATTx;           // 512
    float* mono_e  = vcn + ATTx;           // [B,S] 32768
    float* chunk_e = mono_e + Bx * Sx;     // 32768
    float* beta    = chunk_e + Bx * Sx;    // 32768

    precompute_kernel<<<8193, 256, 0, stream>>>(dec, Wm, bm, Wc, bc, vm, gm, vc, gc,
                                                qm, qc, vmn, vcn);
    energy_kernel<<<8192, 256, 0, stream>>>(key, qm, qc, vmn, vcn,
                                            vbm, rm, vbc, rc, mono_e, chunk_e);
    scan_kernel<<<Bx, 1024, 0, stream>>>(mono_e, chunk_e, prev_att, noise, beta, out);
    context_kernel<<<Bx * 16, 256, 0, stream>>>(beta, value, out);
}